// Round 13
// baseline (176.118 us; speedup 1.0000x reference)
//
#include <hip/hip_runtime.h>
#include <hip/hip_bf16.h>
#include <cstddef>

#define N_FEATS 64
#define NBKT_SHIFT 8       // coarse bucket = dst >> 8 (256 nodes per bucket)
#define EPB 4096           // edges per split block
#define CAP 6144           // per-bucket capacity in pairs[] (mean 4096, 32 sigma)
// NOTE: requires N <= 65536 (src and dst each fit u16). Here N = 50000.

typedef __attribute__((ext_vector_type(8))) short bf16x8;
typedef __attribute__((ext_vector_type(4))) float f32x4;

// round-to-nearest-even f32 -> bf16 bits
__device__ __forceinline__ unsigned f2bf(float f) {
    unsigned x = __float_as_uint(f);
    return (x + 0x7fffu + ((x >> 16) & 1u)) >> 16;
}

// ---------------------------------------------------------------------------
// k_init (1 block): combined weights + bias vector + zero bucket cursors.
//   Wc[64][32] = [Wl1@Wl2 | Wl1@Wr2 | Wr1@Wl2 | Wr1@Wr2]  (bf16)
//   bvec[16]   = [bl1@Wl2 | bl1@Wr2 + bl2]                 (f32)
// ---------------------------------------------------------------------------
__global__ __launch_bounds__(256) void k_init(
        const float* __restrict__ Wl1, const float* __restrict__ bl1,
        const float* __restrict__ Wr1, const float* __restrict__ Wl2,
        const float* __restrict__ bl2, const float* __restrict__ Wr2,
        unsigned short* __restrict__ Wc, float* __restrict__ bvec,
        int* __restrict__ cursor, int nbkt) {
    int tid = threadIdx.x;
    int k = tid & 63, jg = tid >> 6;
    const float* W1 = (jg < 2) ? Wl1 : Wr1;
    const float* W2 = (jg & 1) ? Wr2 : Wl2;
    float acc[8] = {0.f,0.f,0.f,0.f,0.f,0.f,0.f,0.f};
    for (int m = 0; m < 64; ++m) {
        float w1 = W1[k * 64 + m];
        #pragma unroll
        for (int jj = 0; jj < 8; ++jj) acc[jj] += w1 * W2[m * 8 + jj];
    }
    #pragma unroll
    for (int jj = 0; jj < 8; ++jj)
        Wc[k * 32 + jg * 8 + jj] = (unsigned short)f2bf(acc[jj]);
    if (tid < 16) {
        const float* W2b = (tid < 8) ? Wl2 : Wr2;
        float a = 0.f;
        for (int m = 0; m < 64; ++m) a += bl1[m] * W2b[m * 8 + (tid & 7)];
        if (tid >= 8) a += bl2[tid - 8];
        bvec[tid] = a;
    }
    if (tid < nbkt) cursor[tid] = 0;
}

// ---------------------------------------------------------------------------
// Fused dispatch: blocks < nb1 do the bucket-split (LDS stage + count,
// one global chunk-reservation atomic per bucket, place into fixed-stride
// bucket regions — order within bucket is arbitrary, sums don't care).
// Blocks >= nb1 run the MFMA GEMM  Y = X@Wc -> G (bf16 s|s'), T (f32 t|t').
// ---------------------------------------------------------------------------
__global__ __launch_bounds__(256) void k_split_gemm(
        const int* __restrict__ src, const int* __restrict__ dst,
        int* __restrict__ cursor, unsigned* __restrict__ pairs,
        int nEdges, int nbkt, int nb1,
        const float* __restrict__ x,
        const unsigned short* __restrict__ Wc,
        const float* __restrict__ bvec,
        unsigned short* __restrict__ G,   // bf16 [N][16] = [s|s']
        float* __restrict__ T,            // f32  [N][16] = [t|t'] (+bias)
        int nNodes, int nStrips) {
    __shared__ unsigned spr[EPB];
    __shared__ int lh[256];
    __shared__ int lcur[256];
    int tid = threadIdx.x, b = blockIdx.x;

    if (b < nb1) {
        lh[tid] = 0;
        __syncthreads();
        int base = b * EPB;
        int m = nEdges - base; if (m > EPB) m = EPB;
        for (int j = tid; j < m; j += 256) {
            unsigned d = (unsigned)dst[base + j];
            spr[j] = ((unsigned)src[base + j] << 16) | d;
            atomicAdd(&lh[d >> NBKT_SHIFT], 1);
        }
        __syncthreads();
        if (tid < nbkt) lcur[tid] = atomicAdd(&cursor[tid], lh[tid]);
        __syncthreads();
        for (int j = tid; j < m; j += 256) {
            unsigned pr = spr[j];
            int bkt = (pr & 0xffffu) >> NBKT_SHIFT;
            int pos = atomicAdd(&lcur[bkt], 1);
            if (pos < CAP) pairs[(size_t)bkt * CAP + pos] = pr;
        }
        return;
    }

    // ---- MFMA GEMM ----
    int w  = tid >> 6;
    int l  = tid & 63;
    int fc = l & 15;
    int kg = l >> 4;
    bf16x8 bf[2][2];
    #pragma unroll
    for (int ct = 0; ct < 2; ++ct)
        #pragma unroll
        for (int kh = 0; kh < 2; ++kh)
            #pragma unroll
            for (int i = 0; i < 8; ++i) {
                int k = kh * 32 + kg * 8 + i;
                bf[ct][kh][i] = (short)Wc[k * 32 + ct * 16 + fc];
            }
    float bias = bvec[fc];

    for (int strip = b - nb1; strip < nStrips; strip += gridDim.x - nb1) {
        int node0 = strip * 64;
        int arow = node0 + w * 16 + fc;
        int ar = (arow < nNodes) ? arow : (nNodes - 1);
        const float* xp = x + (size_t)ar * 64 + kg * 8;
        float4 xa = *(const float4*)(xp);
        float4 xb = *(const float4*)(xp + 4);
        float4 xc = *(const float4*)(xp + 32);
        float4 xd = *(const float4*)(xp + 36);
        bf16x8 a0, a1;
        a0[0]=(short)f2bf(xa.x); a0[1]=(short)f2bf(xa.y);
        a0[2]=(short)f2bf(xa.z); a0[3]=(short)f2bf(xa.w);
        a0[4]=(short)f2bf(xb.x); a0[5]=(short)f2bf(xb.y);
        a0[6]=(short)f2bf(xb.z); a0[7]=(short)f2bf(xb.w);
        a1[0]=(short)f2bf(xc.x); a1[1]=(short)f2bf(xc.y);
        a1[2]=(short)f2bf(xc.z); a1[3]=(short)f2bf(xc.w);
        a1[4]=(short)f2bf(xd.x); a1[5]=(short)f2bf(xd.y);
        a1[6]=(short)f2bf(xd.z); a1[7]=(short)f2bf(xd.w);

        f32x4 d0 = {0.f, 0.f, 0.f, 0.f};
        f32x4 d1 = {0.f, 0.f, 0.f, 0.f};
        d0 = __builtin_amdgcn_mfma_f32_16x16x32_bf16(a0, bf[0][0], d0, 0, 0, 0);
        d0 = __builtin_amdgcn_mfma_f32_16x16x32_bf16(a1, bf[0][1], d0, 0, 0, 0);
        d1 = __builtin_amdgcn_mfma_f32_16x16x32_bf16(a0, bf[1][0], d1, 0, 0, 0);
        d1 = __builtin_amdgcn_mfma_f32_16x16x32_bf16(a1, bf[1][1], d1, 0, 0, 0);

        #pragma unroll
        for (int r = 0; r < 4; ++r) {
            int node = node0 + w * 16 + kg * 4 + r;
            if (node < nNodes) {
                G[(size_t)node * 16 + fc] = (unsigned short)f2bf(d0[r]);
                T[(size_t)node * 16 + fc] = d1[r] + bias;
            }
        }
    }
}

// ---------------------------------------------------------------------------
// k_agg1: one block per bucket. LDS [256][17] f32 (16 sums + count).
// Stream bucket's pairs: gather G[src] row (32B, L2/L3-hot), 16 ds_add_f32
// + 1 count. Then per node: p = s_sum/cnt + t (bf16), q = s'_sum/cnt + t'.
// ---------------------------------------------------------------------------
__global__ __launch_bounds__(256) void k_agg1(
        const unsigned* __restrict__ pairs,
        const int* __restrict__ cursor,
        const unsigned short* __restrict__ G,
        const float* __restrict__ T,
        unsigned* __restrict__ pbf,       // bf16 [N][8] as [N][4] uints
        float* __restrict__ q,            // f32  [N][8]
        int nNodes) {
    __shared__ float sacc[256][17];
    int tid = threadIdx.x, b = blockIdx.x;
    for (int j = tid; j < 256 * 17; j += 256) ((float*)sacc)[j] = 0.f;
    __syncthreads();
    int cnt = cursor[b]; if (cnt > CAP) cnt = CAP;
    const unsigned* pp = pairs + (size_t)b * CAP;
    for (int e = tid; e < cnt; e += 256) {
        unsigned pr = pp[e];
        int srcid = pr >> 16;
        int dl = pr & 255u;
        const uint4* g4 = (const uint4*)(G + (size_t)srcid * 16);
        uint4 r0 = g4[0];
        uint4 r1 = g4[1];
        float* row = sacc[dl];
        atomicAdd(&row[0],  __uint_as_float(r0.x << 16));
        atomicAdd(&row[1],  __uint_as_float(r0.x & 0xffff0000u));
        atomicAdd(&row[2],  __uint_as_float(r0.y << 16));
        atomicAdd(&row[3],  __uint_as_float(r0.y & 0xffff0000u));
        atomicAdd(&row[4],  __uint_as_float(r0.z << 16));
        atomicAdd(&row[5],  __uint_as_float(r0.z & 0xffff0000u));
        atomicAdd(&row[6],  __uint_as_float(r0.w << 16));
        atomicAdd(&row[7],  __uint_as_float(r0.w & 0xffff0000u));
        atomicAdd(&row[8],  __uint_as_float(r1.x << 16));
        atomicAdd(&row[9],  __uint_as_float(r1.x & 0xffff0000u));
        atomicAdd(&row[10], __uint_as_float(r1.y << 16));
        atomicAdd(&row[11], __uint_as_float(r1.y & 0xffff0000u));
        atomicAdd(&row[12], __uint_as_float(r1.z << 16));
        atomicAdd(&row[13], __uint_as_float(r1.z & 0xffff0000u));
        atomicAdd(&row[14], __uint_as_float(r1.w << 16));
        atomicAdd(&row[15], __uint_as_float(r1.w & 0xffff0000u));
        atomicAdd(&row[16], 1.0f);
    }
    __syncthreads();
    int node = (b << NBKT_SHIFT) + tid;
    if (node < nNodes) {
        float inv = 1.0f / fmaxf(sacc[tid][16], 1.0f);
        const float* trow = T + (size_t)node * 16;
        unsigned o0 = f2bf(sacc[tid][0]*inv + trow[0]) | (f2bf(sacc[tid][1]*inv + trow[1]) << 16);
        unsigned o1 = f2bf(sacc[tid][2]*inv + trow[2]) | (f2bf(sacc[tid][3]*inv + trow[3]) << 16);
        unsigned o2 = f2bf(sacc[tid][4]*inv + trow[4]) | (f2bf(sacc[tid][5]*inv + trow[5]) << 16);
        unsigned o3 = f2bf(sacc[tid][6]*inv + trow[6]) | (f2bf(sacc[tid][7]*inv + trow[7]) << 16);
        *(uint4*)(pbf + (size_t)node * 4) = make_uint4(o0, o1, o2, o3);
        float4 q0, q1;
        q0.x = sacc[tid][8]  * inv + trow[8];
        q0.y = sacc[tid][9]  * inv + trow[9];
        q0.z = sacc[tid][10] * inv + trow[10];
        q0.w = sacc[tid][11] * inv + trow[11];
        q1.x = sacc[tid][12] * inv + trow[12];
        q1.y = sacc[tid][13] * inv + trow[13];
        q1.z = sacc[tid][14] * inv + trow[14];
        q1.w = sacc[tid][15] * inv + trow[15];
        *(float4*)(q + (size_t)node * 8)     = q0;
        *(float4*)(q + (size_t)node * 8 + 4) = q1;
    }
}

// ---------------------------------------------------------------------------
// k_agg2: same pattern over pbf (16B rows): out = p_sum/cnt + q.
// ---------------------------------------------------------------------------
__global__ __launch_bounds__(256) void k_agg2(
        const unsigned* __restrict__ pairs,
        const int* __restrict__ cursor,
        const unsigned* __restrict__ pbf,
        const float* __restrict__ q,
        float* __restrict__ out,
        int nNodes) {
    __shared__ float sacc[256][9];
    int tid = threadIdx.x, b = blockIdx.x;
    for (int j = tid; j < 256 * 9; j += 256) ((float*)sacc)[j] = 0.f;
    __syncthreads();
    int cnt = cursor[b]; if (cnt > CAP) cnt = CAP;
    const unsigned* pp = pairs + (size_t)b * CAP;
    for (int e = tid; e < cnt; e += 256) {
        unsigned pr = pp[e];
        int srcid = pr >> 16;
        int dl = pr & 255u;
        uint4 r = *(const uint4*)(pbf + (size_t)srcid * 4);
        float* row = sacc[dl];
        atomicAdd(&row[0], __uint_as_float(r.x << 16));
        atomicAdd(&row[1], __uint_as_float(r.x & 0xffff0000u));
        atomicAdd(&row[2], __uint_as_float(r.y << 16));
        atomicAdd(&row[3], __uint_as_float(r.y & 0xffff0000u));
        atomicAdd(&row[4], __uint_as_float(r.z << 16));
        atomicAdd(&row[5], __uint_as_float(r.z & 0xffff0000u));
        atomicAdd(&row[6], __uint_as_float(r.w << 16));
        atomicAdd(&row[7], __uint_as_float(r.w & 0xffff0000u));
        atomicAdd(&row[8], 1.0f);
    }
    __syncthreads();
    int node = (b << NBKT_SHIFT) + tid;
    if (node < nNodes) {
        float inv = 1.0f / fmaxf(sacc[tid][8], 1.0f);
        const float* qrow = q + (size_t)node * 8;
        float4 o0, o1;
        o0.x = sacc[tid][0] * inv + qrow[0];
        o0.y = sacc[tid][1] * inv + qrow[1];
        o0.z = sacc[tid][2] * inv + qrow[2];
        o0.w = sacc[tid][3] * inv + qrow[3];
        o1.x = sacc[tid][4] * inv + qrow[4];
        o1.y = sacc[tid][5] * inv + qrow[5];
        o1.z = sacc[tid][6] * inv + qrow[6];
        o1.w = sacc[tid][7] * inv + qrow[7];
        *(float4*)(out + (size_t)node * 8)     = o0;
        *(float4*)(out + (size_t)node * 8 + 4) = o1;
    }
}

static inline size_t align256(size_t v) { return (v + 255) & ~(size_t)255; }

extern "C" void kernel_launch(void* const* d_in, const int* in_sizes, int n_in,
                              void* d_out, int out_size, void* d_ws, size_t ws_size,
                              hipStream_t stream) {
    const float* embeds = (const float*)d_in[0];
    const int*   ei     = (const int*)d_in[1];
    const float* Wl1    = (const float*)d_in[2];
    const float* bl1    = (const float*)d_in[3];
    const float* Wr1    = (const float*)d_in[4];
    const float* Wl2    = (const float*)d_in[5];
    const float* bl2    = (const float*)d_in[6];
    const float* Wr2    = (const float*)d_in[7];

    const int N = in_sizes[0] / N_FEATS;           // 50000
    const int E = in_sizes[1] / 2;                 // 800000
    const int* src = ei;
    const int* dst = ei + E;

    const int NBKT = (N + 255) >> NBKT_SHIFT;      // 196 coarse buckets
    const int NB1  = (E + EPB - 1) / EPB;          // 196 split blocks
    const int NSTRIPS = (N + 63) / 64;             // 782 gemm strips

    // workspace layout
    char* ws = (char*)d_ws;
    size_t off = 0;
    int*            cursor = (int*)(ws + off); off += align256((size_t)NBKT * sizeof(int));
    unsigned short* Wc     = (unsigned short*)(ws + off); off += align256(64 * 32 * sizeof(unsigned short));
    float*          bvec   = (float*)(ws + off); off += align256(16 * sizeof(float));
    unsigned*       pairs  = (unsigned*)(ws + off); off += align256((size_t)NBKT * CAP * sizeof(unsigned));
    unsigned short* G      = (unsigned short*)(ws + off); off += align256((size_t)N * 16 * sizeof(unsigned short));
    float*          T      = (float*)(ws + off); off += align256((size_t)N * 16 * sizeof(float));
    unsigned*       pbf    = (unsigned*)(ws + off); off += align256((size_t)N * 4 * sizeof(unsigned));
    float*          q      = (float*)(ws + off); off += align256((size_t)N * 8 * sizeof(float));
    (void)ws_size;

    // 1. weight combine + cursor zero
    k_init<<<1, 256, 0, stream>>>(Wl1, bl1, Wr1, Wl2, bl2, Wr2, Wc, bvec,
                                  cursor, NBKT);
    // 2. bucket split || MFMA GEMM
    k_split_gemm<<<NB1 + NSTRIPS, 256, 0, stream>>>(
        src, dst, cursor, pairs, E, NBKT, NB1,
        embeds, Wc, bvec, G, T, N, NSTRIPS);
    // 3. layer-1+2 dense-folded aggregation -> pbf, q
    k_agg1<<<NBKT, 256, 0, stream>>>(pairs, cursor, G, T, pbf, q, N);
    // 4. final aggregation -> out
    k_agg2<<<NBKT, 256, 0, stream>>>(pairs, cursor, pbf, q, (float*)d_out, N);
}

// Round 14
// 71.648 us; speedup vs baseline: 2.4581x; 2.4581x over previous
//
#include <hip/hip_runtime.h>
#include <hip/hip_bf16.h>
#include <cstddef>

#define N_FEATS 64
#define NBKT_SHIFT 8       // coarse bucket = dst >> 8 (256 nodes per bucket)
#define EPB 4096           // edges per split block
#define CAP 6144           // per-bucket region capacity (mean 4081, ~32 sigma)
// NOTE: requires N <= 65536 (src fits u16). Here N = 50000.

typedef __attribute__((ext_vector_type(8))) short bf16x8;
typedef __attribute__((ext_vector_type(4))) float f32x4;

// round-to-nearest-even f32 -> bf16 bits
__device__ __forceinline__ unsigned f2bf(float f) {
    unsigned x = __float_as_uint(f);
    return (x + 0x7fffu + ((x >> 16) & 1u)) >> 16;
}

// ---------------------------------------------------------------------------
// k_init (1 block): combined weights + bias vector + zero bucket cursors.
//   Wc[64][32] = [Wl1@Wl2 | Wl1@Wr2 | Wr1@Wl2 | Wr1@Wr2]  (bf16)
//   bvec[16]   = [bl1@Wl2 | bl1@Wr2 + bl2]                 (f32)
// ---------------------------------------------------------------------------
__global__ __launch_bounds__(256) void k_init(
        const float* __restrict__ Wl1, const float* __restrict__ bl1,
        const float* __restrict__ Wr1, const float* __restrict__ Wl2,
        const float* __restrict__ bl2, const float* __restrict__ Wr2,
        unsigned short* __restrict__ Wc, float* __restrict__ bvec,
        int* __restrict__ cursor, int nbkt) {
    int tid = threadIdx.x;
    int k = tid & 63, jg = tid >> 6;
    const float* W1 = (jg < 2) ? Wl1 : Wr1;
    const float* W2 = (jg & 1) ? Wr2 : Wl2;
    float acc[8] = {0.f,0.f,0.f,0.f,0.f,0.f,0.f,0.f};
    for (int m = 0; m < 64; ++m) {
        float w1 = W1[k * 64 + m];
        #pragma unroll
        for (int jj = 0; jj < 8; ++jj) acc[jj] += w1 * W2[m * 8 + jj];
    }
    #pragma unroll
    for (int jj = 0; jj < 8; ++jj)
        Wc[k * 32 + jg * 8 + jj] = (unsigned short)f2bf(acc[jj]);
    if (tid < 16) {
        const float* W2b = (tid < 8) ? Wl2 : Wr2;
        float a = 0.f;
        for (int m = 0; m < 64; ++m) a += bl1[m] * W2b[m * 8 + (tid & 7)];
        if (tid >= 8) a += bl2[tid - 8];
        bvec[tid] = a;
    }
    if (tid < nbkt) cursor[tid] = 0;
}

// ---------------------------------------------------------------------------
// Fused dispatch: blocks < nb1 split edges into fixed-CAP bucket regions
// (LDS stage + count, one global reservation atomic per bucket per block).
// Blocks >= nb1 run the MFMA GEMM  Y = X@Wc -> G (bf16 s|s'), T (f32 t|t').
// ---------------------------------------------------------------------------
__global__ __launch_bounds__(256) void k_split_gemm(
        const int* __restrict__ src, const int* __restrict__ dst,
        int* __restrict__ cursor, unsigned* __restrict__ pairs,
        int nEdges, int nbkt, int nb1,
        const float* __restrict__ x,
        const unsigned short* __restrict__ Wc,
        const float* __restrict__ bvec,
        unsigned short* __restrict__ G,   // bf16 [N][16] = [s|s']
        float* __restrict__ T,            // f32  [N][16] = [t|t'] (+bias)
        int nNodes, int nStrips) {
    __shared__ unsigned spr[EPB];
    __shared__ int lh[256];
    __shared__ int lcur[256];
    int tid = threadIdx.x, b = blockIdx.x;

    if (b < nb1) {
        lh[tid] = 0;
        __syncthreads();
        int base = b * EPB;
        int m = nEdges - base; if (m > EPB) m = EPB;
        for (int j = tid; j < m; j += 256) {
            unsigned d = (unsigned)dst[base + j];
            spr[j] = ((unsigned)src[base + j] << 16) | d;
            atomicAdd(&lh[d >> NBKT_SHIFT], 1);
        }
        __syncthreads();
        if (tid < nbkt) lcur[tid] = atomicAdd(&cursor[tid], lh[tid]);
        __syncthreads();
        for (int j = tid; j < m; j += 256) {
            unsigned pr = spr[j];
            unsigned d = pr & 0xffffu;
            int bkt = d >> NBKT_SHIFT;
            int pos = atomicAdd(&lcur[bkt], 1);
            if (pos < CAP)
                pairs[(size_t)bkt * CAP + pos] = ((pr >> 16) << 8) | (d & 255u);
        }
        return;
    }

    // ---- MFMA GEMM ----
    int w  = tid >> 6;
    int l  = tid & 63;
    int fc = l & 15;
    int kg = l >> 4;
    bf16x8 bf[2][2];
    #pragma unroll
    for (int ct = 0; ct < 2; ++ct)
        #pragma unroll
        for (int kh = 0; kh < 2; ++kh)
            #pragma unroll
            for (int i = 0; i < 8; ++i) {
                int k = kh * 32 + kg * 8 + i;
                bf[ct][kh][i] = (short)Wc[k * 32 + ct * 16 + fc];
            }
    float bias = bvec[fc];

    for (int strip = b - nb1; strip < nStrips; strip += gridDim.x - nb1) {
        int node0 = strip * 64;
        int arow = node0 + w * 16 + fc;
        int ar = (arow < nNodes) ? arow : (nNodes - 1);
        const float* xp = x + (size_t)ar * 64 + kg * 8;
        float4 xa = *(const float4*)(xp);
        float4 xb = *(const float4*)(xp + 4);
        float4 xc = *(const float4*)(xp + 32);
        float4 xd = *(const float4*)(xp + 36);
        bf16x8 a0, a1;
        a0[0]=(short)f2bf(xa.x); a0[1]=(short)f2bf(xa.y);
        a0[2]=(short)f2bf(xa.z); a0[3]=(short)f2bf(xa.w);
        a0[4]=(short)f2bf(xb.x); a0[5]=(short)f2bf(xb.y);
        a0[6]=(short)f2bf(xb.z); a0[7]=(short)f2bf(xb.w);
        a1[0]=(short)f2bf(xc.x); a1[1]=(short)f2bf(xc.y);
        a1[2]=(short)f2bf(xc.z); a1[3]=(short)f2bf(xc.w);
        a1[4]=(short)f2bf(xd.x); a1[5]=(short)f2bf(xd.y);
        a1[6]=(short)f2bf(xd.z); a1[7]=(short)f2bf(xd.w);

        f32x4 d0 = {0.f, 0.f, 0.f, 0.f};
        f32x4 d1 = {0.f, 0.f, 0.f, 0.f};
        d0 = __builtin_amdgcn_mfma_f32_16x16x32_bf16(a0, bf[0][0], d0, 0, 0, 0);
        d0 = __builtin_amdgcn_mfma_f32_16x16x32_bf16(a1, bf[0][1], d0, 0, 0, 0);
        d1 = __builtin_amdgcn_mfma_f32_16x16x32_bf16(a0, bf[1][0], d1, 0, 0, 0);
        d1 = __builtin_amdgcn_mfma_f32_16x16x32_bf16(a1, bf[1][1], d1, 0, 0, 0);

        #pragma unroll
        for (int r = 0; r < 4; ++r) {
            int node = node0 + w * 16 + kg * 4 + r;
            if (node < nNodes) {
                G[(size_t)node * 16 + fc] = (unsigned short)f2bf(d0[r]);
                T[(size_t)node * 16 + fc] = d1[r] + bias;
            }
        }
    }
}

// ---------------------------------------------------------------------------
// k_fsort: one block per bucket; counting sort by dst&255 within the bucket's
// CAP region. Emits counts[], offsets[] (region-space), sorted_src[] (u16).
// ---------------------------------------------------------------------------
__global__ __launch_bounds__(256) void k_fsort(
        const unsigned* __restrict__ pairs,
        const int* __restrict__ cursor,
        int* __restrict__ counts,
        int* __restrict__ offsets,
        unsigned short* __restrict__ sorted_src,
        int nNodes, int nbkt) {
    __shared__ int cnt[256];
    __shared__ int scanbuf[256];
    __shared__ int cur[256];
    int tid = threadIdx.x, b = blockIdx.x;
    int bStart = b * CAP;
    int m = cursor[b]; if (m > CAP) m = CAP;
    cnt[tid] = 0;
    __syncthreads();
    for (int e = tid; e < m; e += 256) {
        atomicAdd(&cnt[pairs[bStart + e] & 255u], 1);
    }
    __syncthreads();
    int v = cnt[tid];
    scanbuf[tid] = v;
    __syncthreads();
    for (int d = 1; d < 256; d <<= 1) {
        int t = (tid >= d) ? scanbuf[tid - d] : 0;
        __syncthreads();
        scanbuf[tid] += t;
        __syncthreads();
    }
    int excl = scanbuf[tid] - v;
    int node = (b << NBKT_SHIFT) + tid;
    if (node < nNodes) { counts[node] = v; offsets[node] = bStart + excl; }
    cur[tid] = bStart + excl;
    __syncthreads();
    for (int e = tid; e < m; e += 256) {
        unsigned pr = pairs[bStart + e];
        int pos = atomicAdd(&cur[pr & 255u], 1);
        sorted_src[pos] = (unsigned short)(pr >> 8);
    }
}

// ---------------------------------------------------------------------------
// p = mean-gather(s) + t  (-> bf16),  q = mean-gather(s') + t'  (-> f32).
// 1 node/wave; 8 edge-groups x 8 lanes x 4B (uint = 2 bf16) per G-row.
// ---------------------------------------------------------------------------
__global__ __launch_bounds__(256) void k_gather2(
        const unsigned* __restrict__ G,     // [N][8] uints
        const float* __restrict__ T,        // [N][16]
        const int* __restrict__ counts,
        const int* __restrict__ offsets,
        const unsigned short* __restrict__ ss,
        unsigned* __restrict__ pbf,         // [N][4] uints (8 bf16)
        float* __restrict__ q,              // [N][8]
        int nNodes) {
    int tid = threadIdx.x;
    int slot = tid >> 6, lane = tid & 63;
    int g = lane >> 3, t = lane & 7;
    int node = blockIdx.x * 4 + slot;
    if (node >= nNodes) return;
    int cnt = counts[node], off = offsets[node];
    float a0 = 0.f, a1 = 0.f;
    int id = (g < cnt) ? (int)ss[off + g] : -1;
    for (int base = 0; base < cnt; base += 8) {
        int en = base + 8 + g;
        int idn = (en < cnt) ? (int)ss[off + en] : -1;
        if (id >= 0) {
            unsigned r = G[(size_t)id * 8 + t];
            a0 += __uint_as_float(r << 16);
            a1 += __uint_as_float(r & 0xffff0000u);
        }
        id = idn;
    }
    a0 += __shfl_xor(a0, 8);  a1 += __shfl_xor(a1, 8);
    a0 += __shfl_xor(a0, 16); a1 += __shfl_xor(a1, 16);
    a0 += __shfl_xor(a0, 32); a1 += __shfl_xor(a1, 32);
    if (g == 0) {
        float inv = 1.0f / fmaxf((float)cnt, 1.0f);
        float2 tv = *(const float2*)&T[(size_t)node * 16 + 2 * t];
        float r0 = a0 * inv + tv.x;
        float r1 = a1 * inv + tv.y;
        if (t < 4) pbf[(size_t)node * 4 + t] = f2bf(r0) | (f2bf(r1) << 16);
        else ((float2*)q)[(size_t)node * 4 + (t - 4)] = make_float2(r0, r1);
    }
}

// ---------------------------------------------------------------------------
// out = mean-gather(p) + q.  1 node/wave; 16 edge-groups x 4 lanes x uint.
// ---------------------------------------------------------------------------
__global__ __launch_bounds__(256) void k_final(
        const unsigned* __restrict__ pbf,   // [N][4] uints (8 bf16)
        const float* __restrict__ q,        // [N][8]
        const int* __restrict__ counts,
        const int* __restrict__ offsets,
        const unsigned short* __restrict__ ss,
        float* __restrict__ out,
        int nNodes) {
    int tid = threadIdx.x;
    int slot = tid >> 6, lane = tid & 63;
    int eg = lane >> 2, t = lane & 3;
    int node = blockIdx.x * 4 + slot;
    if (node >= nNodes) return;
    int cnt = counts[node], off = offsets[node];
    float a0 = 0.f, a1 = 0.f;
    int id = (eg < cnt) ? (int)ss[off + eg] : -1;
    for (int base = 0; base < cnt; base += 16) {
        int en = base + 16 + eg;
        int idn = (en < cnt) ? (int)ss[off + en] : -1;
        if (id >= 0) {
            unsigned r = pbf[(size_t)id * 4 + t];
            a0 += __uint_as_float(r << 16);
            a1 += __uint_as_float(r & 0xffff0000u);
        }
        id = idn;
    }
    a0 += __shfl_xor(a0, 4);  a1 += __shfl_xor(a1, 4);
    a0 += __shfl_xor(a0, 8);  a1 += __shfl_xor(a1, 8);
    a0 += __shfl_xor(a0, 16); a1 += __shfl_xor(a1, 16);
    a0 += __shfl_xor(a0, 32); a1 += __shfl_xor(a1, 32);
    if (eg == 0) {
        float inv = 1.0f / fmaxf((float)cnt, 1.0f);
        float2 qv = ((const float2*)q)[(size_t)node * 4 + t];
        ((float2*)out)[(size_t)node * 4 + t] =
            make_float2(a0 * inv + qv.x, a1 * inv + qv.y);
    }
}

static inline size_t align256(size_t v) { return (v + 255) & ~(size_t)255; }

extern "C" void kernel_launch(void* const* d_in, const int* in_sizes, int n_in,
                              void* d_out, int out_size, void* d_ws, size_t ws_size,
                              hipStream_t stream) {
    const float* embeds = (const float*)d_in[0];
    const int*   ei     = (const int*)d_in[1];
    const float* Wl1    = (const float*)d_in[2];
    const float* bl1    = (const float*)d_in[3];
    const float* Wr1    = (const float*)d_in[4];
    const float* Wl2    = (const float*)d_in[5];
    const float* bl2    = (const float*)d_in[6];
    const float* Wr2    = (const float*)d_in[7];

    const int N = in_sizes[0] / N_FEATS;           // 50000
    const int E = in_sizes[1] / 2;                 // 800000
    const int* src = ei;
    const int* dst = ei + E;

    const int NBKT = (N + 255) >> NBKT_SHIFT;      // 196 coarse buckets
    const int NB1  = (E + EPB - 1) / EPB;          // 196 split blocks
    const int NSTRIPS = (N + 63) / 64;             // 782 gemm strips

    // workspace layout
    char* ws = (char*)d_ws;
    size_t off = 0;
    int*            cursor     = (int*)(ws + off); off += align256((size_t)NBKT * sizeof(int));
    int*            counts     = (int*)(ws + off); off += align256((size_t)N * sizeof(int));
    int*            offsets    = (int*)(ws + off); off += align256((size_t)N * sizeof(int));
    unsigned short* Wc         = (unsigned short*)(ws + off); off += align256(64 * 32 * sizeof(unsigned short));
    float*          bvec       = (float*)(ws + off); off += align256(16 * sizeof(float));
    unsigned*       pairs      = (unsigned*)(ws + off); off += align256((size_t)NBKT * CAP * sizeof(unsigned));
    unsigned short* sorted_src = (unsigned short*)(ws + off); off += align256((size_t)NBKT * CAP * sizeof(unsigned short));
    unsigned*       G          = (unsigned*)(ws + off); off += align256((size_t)N * 16 * sizeof(unsigned short));
    float*          T          = (float*)(ws + off); off += align256((size_t)N * 16 * sizeof(float));
    unsigned*       pbf        = (unsigned*)(ws + off); off += align256((size_t)N * 4 * sizeof(unsigned));
    float*          q          = (float*)(ws + off); off += align256((size_t)N * 8 * sizeof(float));
    (void)ws_size;

    // 1. weight combine + cursor zero
    k_init<<<1, 256, 0, stream>>>(Wl1, bl1, Wr1, Wl2, bl2, Wr2, Wc, bvec,
                                  cursor, NBKT);
    // 2. bucket split (CAP regions) || MFMA GEMM
    k_split_gemm<<<NB1 + NSTRIPS, 256, 0, stream>>>(
        src, dst, cursor, pairs, E, NBKT, NB1,
        embeds, Wc, bvec, (unsigned short*)G, T, N, NSTRIPS);
    // 3. per-bucket counting sort -> counts/offsets/sorted_src
    k_fsort<<<NBKT, 256, 0, stream>>>(pairs, cursor, counts, offsets,
                                      sorted_src, N, NBKT);
    // 4. p,q = mean-gather(G) + T
    k_gather2<<<(N + 3) / 4, 256, 0, stream>>>(G, T, counts, offsets, sorted_src,
                                               pbf, q, N);
    // 5. out = mean-gather(p) + q
    k_final<<<(N + 3) / 4, 256, 0, stream>>>(pbf, q, counts, offsets, sorted_src,
                                             (float*)d_out, N);
}

// Round 15
// 62.739 us; speedup vs baseline: 2.8072x; 1.1420x over previous
//
#include <hip/hip_runtime.h>
#include <hip/hip_bf16.h>
#include <cstddef>

#define N_FEATS 64
#define NBKT_SHIFT 8       // coarse bucket = dst >> 8 (256 nodes per bucket)
#define EPB 4096           // edges per split block
#define CAP 6144           // per-bucket region capacity (mean 4081, ~32 sigma)
// NOTE: requires N <= 65536 (src fits u16). Here N = 50000.

typedef __attribute__((ext_vector_type(8))) short bf16x8;
typedef __attribute__((ext_vector_type(4))) float f32x4;

// round-to-nearest-even f32 -> bf16 bits
__device__ __forceinline__ unsigned f2bf(float f) {
    unsigned x = __float_as_uint(f);
    return (x + 0x7fffu + ((x >> 16) & 1u)) >> 16;
}

// ---------------------------------------------------------------------------
// k_init (1 block): combined weights + bias vector + zero bucket cursors.
//   Wc[64][32] = [Wl1@Wl2 | Wl1@Wr2 | Wr1@Wl2 | Wr1@Wr2]  (bf16)
//   bvec[16]   = [bl1@Wl2 | bl1@Wr2 + bl2]                 (f32)
// ---------------------------------------------------------------------------
__global__ __launch_bounds__(256) void k_init(
        const float* __restrict__ Wl1, const float* __restrict__ bl1,
        const float* __restrict__ Wr1, const float* __restrict__ Wl2,
        const float* __restrict__ bl2, const float* __restrict__ Wr2,
        unsigned short* __restrict__ Wc, float* __restrict__ bvec,
        int* __restrict__ cursor, int nbkt) {
    int tid = threadIdx.x;
    int k = tid & 63, jg = tid >> 6;
    const float* W1 = (jg < 2) ? Wl1 : Wr1;
    const float* W2 = (jg & 1) ? Wr2 : Wl2;
    float acc[8] = {0.f,0.f,0.f,0.f,0.f,0.f,0.f,0.f};
    for (int m = 0; m < 64; ++m) {
        float w1 = W1[k * 64 + m];
        #pragma unroll
        for (int jj = 0; jj < 8; ++jj) acc[jj] += w1 * W2[m * 8 + jj];
    }
    #pragma unroll
    for (int jj = 0; jj < 8; ++jj)
        Wc[k * 32 + jg * 8 + jj] = (unsigned short)f2bf(acc[jj]);
    if (tid < 16) {
        const float* W2b = (tid < 8) ? Wl2 : Wr2;
        float a = 0.f;
        for (int m = 0; m < 64; ++m) a += bl1[m] * W2b[m * 8 + (tid & 7)];
        if (tid >= 8) a += bl2[tid - 8];
        bvec[tid] = a;
    }
    if (tid < nbkt) cursor[tid] = 0;
}

// ---------------------------------------------------------------------------
// Fused dispatch: blocks < nb1 split edges into fixed-CAP bucket regions
// (LDS stage + count, one global reservation atomic per bucket per block).
// Blocks >= nb1 run the MFMA GEMM  Y = X@Wc -> G (bf16 s|s'), T (f32 t|t').
// ---------------------------------------------------------------------------
__global__ __launch_bounds__(256) void k_split_gemm(
        const int* __restrict__ src, const int* __restrict__ dst,
        int* __restrict__ cursor, unsigned* __restrict__ pairs,
        int nEdges, int nbkt, int nb1,
        const float* __restrict__ x,
        const unsigned short* __restrict__ Wc,
        const float* __restrict__ bvec,
        unsigned short* __restrict__ G,   // bf16 [N][16] = [s|s']
        float* __restrict__ T,            // f32  [N][16] = [t|t'] (+bias)
        int nNodes, int nStrips) {
    __shared__ unsigned spr[EPB];
    __shared__ int lh[256];
    __shared__ int lcur[256];
    int tid = threadIdx.x, b = blockIdx.x;

    if (b < nb1) {
        lh[tid] = 0;
        __syncthreads();
        int base = b * EPB;
        int m = nEdges - base; if (m > EPB) m = EPB;
        for (int j = tid; j < m; j += 256) {
            unsigned d = (unsigned)dst[base + j];
            spr[j] = ((unsigned)src[base + j] << 16) | d;
            atomicAdd(&lh[d >> NBKT_SHIFT], 1);
        }
        __syncthreads();
        if (tid < nbkt) lcur[tid] = atomicAdd(&cursor[tid], lh[tid]);
        __syncthreads();
        for (int j = tid; j < m; j += 256) {
            unsigned pr = spr[j];
            unsigned d = pr & 0xffffu;
            int bkt = d >> NBKT_SHIFT;
            int pos = atomicAdd(&lcur[bkt], 1);
            if (pos < CAP)
                pairs[(size_t)bkt * CAP + pos] = ((pr >> 16) << 8) | (d & 255u);
        }
        return;
    }

    // ---- MFMA GEMM ----
    int w  = tid >> 6;
    int l  = tid & 63;
    int fc = l & 15;
    int kg = l >> 4;
    bf16x8 bf[2][2];
    #pragma unroll
    for (int ct = 0; ct < 2; ++ct)
        #pragma unroll
        for (int kh = 0; kh < 2; ++kh)
            #pragma unroll
            for (int i = 0; i < 8; ++i) {
                int k = kh * 32 + kg * 8 + i;
                bf[ct][kh][i] = (short)Wc[k * 32 + ct * 16 + fc];
            }
    float bias = bvec[fc];

    for (int strip = b - nb1; strip < nStrips; strip += gridDim.x - nb1) {
        int node0 = strip * 64;
        int arow = node0 + w * 16 + fc;
        int ar = (arow < nNodes) ? arow : (nNodes - 1);
        const float* xp = x + (size_t)ar * 64 + kg * 8;
        float4 xa = *(const float4*)(xp);
        float4 xb = *(const float4*)(xp + 4);
        float4 xc = *(const float4*)(xp + 32);
        float4 xd = *(const float4*)(xp + 36);
        bf16x8 a0, a1;
        a0[0]=(short)f2bf(xa.x); a0[1]=(short)f2bf(xa.y);
        a0[2]=(short)f2bf(xa.z); a0[3]=(short)f2bf(xa.w);
        a0[4]=(short)f2bf(xb.x); a0[5]=(short)f2bf(xb.y);
        a0[6]=(short)f2bf(xb.z); a0[7]=(short)f2bf(xb.w);
        a1[0]=(short)f2bf(xc.x); a1[1]=(short)f2bf(xc.y);
        a1[2]=(short)f2bf(xc.z); a1[3]=(short)f2bf(xc.w);
        a1[4]=(short)f2bf(xd.x); a1[5]=(short)f2bf(xd.y);
        a1[6]=(short)f2bf(xd.z); a1[7]=(short)f2bf(xd.w);

        f32x4 d0 = {0.f, 0.f, 0.f, 0.f};
        f32x4 d1 = {0.f, 0.f, 0.f, 0.f};
        d0 = __builtin_amdgcn_mfma_f32_16x16x32_bf16(a0, bf[0][0], d0, 0, 0, 0);
        d0 = __builtin_amdgcn_mfma_f32_16x16x32_bf16(a1, bf[0][1], d0, 0, 0, 0);
        d1 = __builtin_amdgcn_mfma_f32_16x16x32_bf16(a0, bf[1][0], d1, 0, 0, 0);
        d1 = __builtin_amdgcn_mfma_f32_16x16x32_bf16(a1, bf[1][1], d1, 0, 0, 0);

        #pragma unroll
        for (int r = 0; r < 4; ++r) {
            int node = node0 + w * 16 + kg * 4 + r;
            if (node < nNodes) {
                G[(size_t)node * 16 + fc] = (unsigned short)f2bf(d0[r]);
                T[(size_t)node * 16 + fc] = d1[r] + bias;
            }
        }
    }
}

// ---------------------------------------------------------------------------
// k_fsort: one block per bucket; counting sort by dst&255 within the bucket's
// CAP region. Emits counts[], offsets[] (region-space), sorted_src[] (u16).
// ---------------------------------------------------------------------------
__global__ __launch_bounds__(256) void k_fsort(
        const unsigned* __restrict__ pairs,
        const int* __restrict__ cursor,
        int* __restrict__ counts,
        int* __restrict__ offsets,
        unsigned short* __restrict__ sorted_src,
        int nNodes, int nbkt) {
    __shared__ int cnt[256];
    __shared__ int scanbuf[256];
    __shared__ int cur[256];
    int tid = threadIdx.x, b = blockIdx.x;
    int bStart = b * CAP;
    int m = cursor[b]; if (m > CAP) m = CAP;
    cnt[tid] = 0;
    __syncthreads();
    for (int e = tid; e < m; e += 256) {
        atomicAdd(&cnt[pairs[bStart + e] & 255u], 1);
    }
    __syncthreads();
    int v = cnt[tid];
    scanbuf[tid] = v;
    __syncthreads();
    for (int d = 1; d < 256; d <<= 1) {
        int t = (tid >= d) ? scanbuf[tid - d] : 0;
        __syncthreads();
        scanbuf[tid] += t;
        __syncthreads();
    }
    int excl = scanbuf[tid] - v;
    int node = (b << NBKT_SHIFT) + tid;
    if (node < nNodes) { counts[node] = v; offsets[node] = bStart + excl; }
    cur[tid] = bStart + excl;
    __syncthreads();
    for (int e = tid; e < m; e += 256) {
        unsigned pr = pairs[bStart + e];
        int pos = atomicAdd(&cur[pr & 255u], 1);
        sorted_src[pos] = (unsigned short)(pr >> 8);
    }
}

// ---------------------------------------------------------------------------
// p = mean-gather(s) + t  (-> bf16),  q = mean-gather(s') + t'  (-> f32).
// 2 nodes/wave: half = lane>>5; 8 edge-groups x 4 lanes x uint2 (8B) per
// 32B G-row. Reduce via shfl_xor 4/8/16 (stays within the 32-lane half).
// ---------------------------------------------------------------------------
__global__ __launch_bounds__(256) void k_gather2(
        const unsigned* __restrict__ G,     // [N][8] uints
        const float* __restrict__ T,        // [N][16]
        const int* __restrict__ counts,
        const int* __restrict__ offsets,
        const unsigned short* __restrict__ ss,
        unsigned* __restrict__ pbf,         // [N][4] uints (8 bf16)
        float* __restrict__ q,              // [N][8]
        int nNodes) {
    int tid  = threadIdx.x;
    int wave = tid >> 6, lane = tid & 63;
    int half = lane >> 5;
    int eg   = (lane >> 2) & 7;   // 8 edge groups
    int t4   = lane & 3;          // uint2 slot (8B): values t4*4 .. t4*4+3
    int node = blockIdx.x * 8 + wave * 2 + half;
    if (node >= nNodes) return;
    int cnt = counts[node], off = offsets[node];
    const uint2* G2 = (const uint2*)G;      // 4 x uint2 per row

    float a0 = 0.f, a1 = 0.f, a2 = 0.f, a3 = 0.f;
    int id = (eg < cnt) ? (int)ss[off + eg] : -1;
    for (int base = 0; base < cnt; base += 8) {
        int en = base + 8 + eg;
        int idn = (en < cnt) ? (int)ss[off + en] : -1;
        if (id >= 0) {
            uint2 r = G2[(size_t)id * 4 + t4];
            a0 += __uint_as_float(r.x << 16);
            a1 += __uint_as_float(r.x & 0xffff0000u);
            a2 += __uint_as_float(r.y << 16);
            a3 += __uint_as_float(r.y & 0xffff0000u);
        }
        id = idn;
    }
    a0 += __shfl_xor(a0, 4);  a1 += __shfl_xor(a1, 4);
    a2 += __shfl_xor(a2, 4);  a3 += __shfl_xor(a3, 4);
    a0 += __shfl_xor(a0, 8);  a1 += __shfl_xor(a1, 8);
    a2 += __shfl_xor(a2, 8);  a3 += __shfl_xor(a3, 8);
    a0 += __shfl_xor(a0, 16); a1 += __shfl_xor(a1, 16);
    a2 += __shfl_xor(a2, 16); a3 += __shfl_xor(a3, 16);

    if (eg == 0) {
        float inv = 1.0f / fmaxf((float)cnt, 1.0f);
        float4 tv = *(const float4*)&T[(size_t)node * 16 + t4 * 4];
        float r0 = a0 * inv + tv.x;
        float r1 = a1 * inv + tv.y;
        float r2 = a2 * inv + tv.z;
        float r3 = a3 * inv + tv.w;
        if (t4 < 2) {
            // s -> p (bf16): words 2*t4, 2*t4+1
            uint2 o;
            o.x = f2bf(r0) | (f2bf(r1) << 16);
            o.y = f2bf(r2) | (f2bf(r3) << 16);
            *(uint2*)(pbf + (size_t)node * 4 + t4 * 2) = o;
        } else {
            // s' -> q (f32): floats (t4-2)*4 .. +3
            float4 o; o.x = r0; o.y = r1; o.z = r2; o.w = r3;
            *(float4*)(q + (size_t)node * 8 + (t4 - 2) * 4) = o;
        }
    }
}

// ---------------------------------------------------------------------------
// out = mean-gather(p) + q.  2 nodes/wave: half = lane>>5; 16 edge-groups x
// 2 lanes x uint2 (8B) per 16B pbf-row. Reduce shfl_xor 2/4/8/16.
// ---------------------------------------------------------------------------
__global__ __launch_bounds__(256) void k_final(
        const unsigned* __restrict__ pbf,   // [N][4] uints (8 bf16)
        const float* __restrict__ q,        // [N][8]
        const int* __restrict__ counts,
        const int* __restrict__ offsets,
        const unsigned short* __restrict__ ss,
        float* __restrict__ out,
        int nNodes) {
    int tid  = threadIdx.x;
    int wave = tid >> 6, lane = tid & 63;
    int half = lane >> 5;
    int eg   = (lane >> 1) & 15;  // 16 edge groups
    int t2   = lane & 1;          // uint2 slot: values t2*4 .. t2*4+3
    int node = blockIdx.x * 8 + wave * 2 + half;
    if (node >= nNodes) return;
    int cnt = counts[node], off = offsets[node];
    const uint2* P2 = (const uint2*)pbf;    // 2 x uint2 per row

    float a0 = 0.f, a1 = 0.f, a2 = 0.f, a3 = 0.f;
    int id = (eg < cnt) ? (int)ss[off + eg] : -1;
    for (int base = 0; base < cnt; base += 16) {
        int en = base + 16 + eg;
        int idn = (en < cnt) ? (int)ss[off + en] : -1;
        if (id >= 0) {
            uint2 r = P2[(size_t)id * 2 + t2];
            a0 += __uint_as_float(r.x << 16);
            a1 += __uint_as_float(r.x & 0xffff0000u);
            a2 += __uint_as_float(r.y << 16);
            a3 += __uint_as_float(r.y & 0xffff0000u);
        }
        id = idn;
    }
    a0 += __shfl_xor(a0, 2);  a1 += __shfl_xor(a1, 2);
    a2 += __shfl_xor(a2, 2);  a3 += __shfl_xor(a3, 2);
    a0 += __shfl_xor(a0, 4);  a1 += __shfl_xor(a1, 4);
    a2 += __shfl_xor(a2, 4);  a3 += __shfl_xor(a3, 4);
    a0 += __shfl_xor(a0, 8);  a1 += __shfl_xor(a1, 8);
    a2 += __shfl_xor(a2, 8);  a3 += __shfl_xor(a3, 8);
    a0 += __shfl_xor(a0, 16); a1 += __shfl_xor(a1, 16);
    a2 += __shfl_xor(a2, 16); a3 += __shfl_xor(a3, 16);

    if (eg == 0) {
        float inv = 1.0f / fmaxf((float)cnt, 1.0f);
        float4 qv = *(const float4*)&q[(size_t)node * 8 + t2 * 4];
        float4 o;
        o.x = a0 * inv + qv.x; o.y = a1 * inv + qv.y;
        o.z = a2 * inv + qv.z; o.w = a3 * inv + qv.w;
        *(float4*)(out + (size_t)node * 8 + t2 * 4) = o;
    }
}

static inline size_t align256(size_t v) { return (v + 255) & ~(size_t)255; }

extern "C" void kernel_launch(void* const* d_in, const int* in_sizes, int n_in,
                              void* d_out, int out_size, void* d_ws, size_t ws_size,
                              hipStream_t stream) {
    const float* embeds = (const float*)d_in[0];
    const int*   ei     = (const int*)d_in[1];
    const float* Wl1    = (const float*)d_in[2];
    const float* bl1    = (const float*)d_in[3];
    const float* Wr1    = (const float*)d_in[4];
    const float* Wl2    = (const float*)d_in[5];
    const float* bl2    = (const float*)d_in[6];
    const float* Wr2    = (const float*)d_in[7];

    const int N = in_sizes[0] / N_FEATS;           // 50000
    const int E = in_sizes[1] / 2;                 // 800000
    const int* src = ei;
    const int* dst = ei + E;

    const int NBKT = (N + 255) >> NBKT_SHIFT;      // 196 coarse buckets
    const int NB1  = (E + EPB - 1) / EPB;          // 196 split blocks
    const int NSTRIPS = (N + 63) / 64;             // 782 gemm strips

    // workspace layout
    char* ws = (char*)d_ws;
    size_t off = 0;
    int*            cursor     = (int*)(ws + off); off += align256((size_t)NBKT * sizeof(int));
    int*            counts     = (int*)(ws + off); off += align256((size_t)N * sizeof(int));
    int*            offsets    = (int*)(ws + off); off += align256((size_t)N * sizeof(int));
    unsigned short* Wc         = (unsigned short*)(ws + off); off += align256(64 * 32 * sizeof(unsigned short));
    float*          bvec       = (float*)(ws + off); off += align256(16 * sizeof(float));
    unsigned*       pairs      = (unsigned*)(ws + off); off += align256((size_t)NBKT * CAP * sizeof(unsigned));
    unsigned short* sorted_src = (unsigned short*)(ws + off); off += align256((size_t)NBKT * CAP * sizeof(unsigned short));
    unsigned*       G          = (unsigned*)(ws + off); off += align256((size_t)N * 16 * sizeof(unsigned short));
    float*          T          = (float*)(ws + off); off += align256((size_t)N * 16 * sizeof(float));
    unsigned*       pbf        = (unsigned*)(ws + off); off += align256((size_t)N * 4 * sizeof(unsigned));
    float*          q          = (float*)(ws + off); off += align256((size_t)N * 8 * sizeof(float));
    (void)ws_size;

    // 1. weight combine + cursor zero
    k_init<<<1, 256, 0, stream>>>(Wl1, bl1, Wr1, Wl2, bl2, Wr2, Wc, bvec,
                                  cursor, NBKT);
    // 2. bucket split (CAP regions) || MFMA GEMM
    k_split_gemm<<<NB1 + NSTRIPS, 256, 0, stream>>>(
        src, dst, cursor, pairs, E, NBKT, NB1,
        embeds, Wc, bvec, (unsigned short*)G, T, N, NSTRIPS);
    // 3. per-bucket counting sort -> counts/offsets/sorted_src
    k_fsort<<<NBKT, 256, 0, stream>>>(pairs, cursor, counts, offsets,
                                      sorted_src, N, NBKT);
    // 4. p,q = mean-gather(G) + T   (2 nodes/wave)
    k_gather2<<<(N + 7) / 8, 256, 0, stream>>>(G, T, counts, offsets, sorted_src,
                                               pbf, q, N);
    // 5. out = mean-gather(p) + q   (2 nodes/wave)
    k_final<<<(N + 7) / 8, 256, 0, stream>>>(pbf, q, counts, offsets, sorted_src,
                                             (float*)d_out, N);
}